// Round 6
// baseline (427.625 us; speedup 1.0000x reference)
//
#include <hip/hip_runtime.h>
#include <math.h>

#define NN 100000   // nodes
#define NE 50000    // edges (segments of first aggregate)
#define NSEG (NE + NN)
#define DD 128      // feature dim

// bucketing for the binned CSR build: bucket = id >> 8 (256 segments/bucket)
#define NBE 196                 // ceil(50000/256)
#define NBV 391                 // ceil(100000/256)
#define NB  (NBE + NBV)         // 587
#define CAP_E 8960              // slab cap per edge bucket (mean 8192, sigma~90)
#define CAP_V 4608              // slab cap per vertex bucket (mean 4096, sigma~64)

typedef short bf16x8 __attribute__((ext_vector_type(8)));
typedef float f32x4 __attribute__((ext_vector_type(4)));
typedef float v2f __attribute__((ext_vector_type(2)));

static __device__ __forceinline__ float gelu_exact(float x) {
  return 0.5f * x * (1.0f + erff(x * 0.70710678118654752f));
}

static __device__ __forceinline__ int bucket_base(int g) {
  return (g < NBE) ? g * CAP_E : NBE * CAP_E + (g - NBE) * CAP_V;
}

// unpack 2 bf16 from a uint and accumulate into a float2 (v_pk_add_f32)
static __device__ __forceinline__ void acc2(v2f& a, unsigned u) {
  union { unsigned i; float f; } lo, hi;
  lo.i = u << 16;
  hi.i = u & 0xFFFF0000u;
  v2f t;
  t.x = lo.f;
  t.y = hi.f;
  a += t;
}

// pack 2 fp32 -> bf16x2 (round to nearest even)
static __device__ __forceinline__ unsigned pack_bf16x2(float a, float b) {
  unsigned ua = __float_as_uint(a), ub = __float_as_uint(b);
  ua = (ua + 0x7FFFu + ((ua >> 16) & 1u)) >> 16;
  ub = (ub + 0x7FFFu + ((ub >> 16) & 1u)) >> 16;
  return ua | (ub << 16);
}

static __device__ __forceinline__ unsigned short bf16_rne(float a) {
  unsigned ua = __float_as_uint(a);
  ua = (ua + 0x7FFFu + ((ua >> 16) & 1u)) >> 16;
  return (unsigned short)ua;
}

// ---------------- K0: init bucket cursors + Wt[n][k] = bf16(W[k][n]) ----------------
__global__ __launch_bounds__(256) void k_init(int* __restrict__ gcur,
                                              const float* __restrict__ W,
                                              unsigned short* __restrict__ Wt) {
  const int b = blockIdx.x;
  if (b < 64) {
    int idx = b * 256 + threadIdx.x;  // 16384 = 128*128
    int k = idx >> 7, n = idx & 127;
    Wt[n * 128 + k] = bf16_rne(W[idx]);
  } else {
    int g = (b - 64) * 256 + threadIdx.x;
    if (g < NB) gcur[g] = bucket_base(g);
  }
}

// ---------------- K1: Xp = X @ W via bf16 MFMA; writes CHUNK-MAJOR bf16 ----------------
// Xb2c layout: [4 chunks][NN][32 bf16]  (chunk c holds feature cols [32c, 32c+32))
// mfma_f32_16x16x32_bf16 layouts:
//   A frag: lane l holds A[m][k], m = l&15, k = (l>>4)*8 + e (8 contiguous k)
//   B frag: lane l holds B[k][n], n = l&15, k = (l>>4)*8 + e
//   C/D   : lane l, reg r holds D[(l>>4)*4 + r][l&15]
__global__ __launch_bounds__(256) void k_gemm(const float* __restrict__ X,
                                              const unsigned short* __restrict__ Wt,
                                              unsigned short* __restrict__ Xb2c) {
  const int tid = threadIdx.x;
  const int w = tid >> 6;          // wave 0..3
  const int l = tid & 63;
  const int lm = l & 15;           // A row / B col within tile
  const int lk = l >> 4;           // k-group 0..3
  const int R = blockIdx.x * 64 + w * 16;
  const int arow = R + lm;
  const bool rowok = arow < NN;
  const f32x4* __restrict__ X4 = (const f32x4*)X;
  const uint4* __restrict__ Wt4 = (const uint4*)Wt;

  f32x4 acc[8];
#pragma unroll
  for (int t = 0; t < 8; ++t) acc[t] = (f32x4)(0.f);

  for (int c = 0; c < 4; ++c) {
    const int k0 = c * 32 + lk * 8;
    f32x4 x0 = (f32x4)(0.f), x1 = (f32x4)(0.f);
    if (rowok) {
      x0 = __builtin_nontemporal_load(&X4[arow * 32 + (k0 >> 2)]);
      x1 = __builtin_nontemporal_load(&X4[arow * 32 + (k0 >> 2) + 1]);
    }
    union { bf16x8 v; uint4 u; } a;
    a.u.x = pack_bf16x2(x0.x, x0.y);
    a.u.y = pack_bf16x2(x0.z, x0.w);
    a.u.z = pack_bf16x2(x1.x, x1.y);
    a.u.w = pack_bf16x2(x1.z, x1.w);
#pragma unroll
    for (int t = 0; t < 8; ++t) {
      union { bf16x8 v; uint4 u; } b;
      b.u = Wt4[(t * 16 + lm) * 16 + c * 4 + lk];  // 8 bf16 = 16B, k-contiguous
      acc[t] = __builtin_amdgcn_mfma_f32_16x16x32_bf16(a.v, b.v, acc[t], 0, 0, 0);
    }
  }

  const int drow = R + lk * 4;
#pragma unroll
  for (int r = 0; r < 4; ++r) {
    const int row = drow + r;
    if (row < NN) {
#pragma unroll
      for (int t = 0; t < 8; ++t) {
        // col = t*16+lm; chunk = t>>1; within-chunk ushort = (t&1)*16 + lm
        Xb2c[((size_t)(t >> 1) * NN + row) * 32 + (t & 1) * 16 + lm] =
            bf16_rne(acc[t][r]);
      }
    }
  }
}

// ---------------- K2: bin incidences into bucket slabs ----------------
// staged item: (seg & 255) << 17 | value  (both values < 2^17)
__global__ __launch_bounds__(256) void k_pass1(const int* __restrict__ vertex,
                                               const int* __restrict__ edges,
                                               int* __restrict__ gcur,
                                               int* __restrict__ S, int nnz) {
  __shared__ int hist[NB];
  const int tid = threadIdx.x;
  for (int b = tid; b < NB; b += 256) hist[b] = 0;
  __syncthreads();
  const int base = blockIdx.x * 4096;
#pragma unroll
  for (int k = 0; k < 16; ++k) {
    int i = base + tid + k * 256;
    if (i < nnz) {
      atomicAdd(&hist[edges[i] >> 8], 1);
      atomicAdd(&hist[NBE + (vertex[i] >> 8)], 1);
    }
  }
  __syncthreads();
  for (int b = tid; b < NB; b += 256) {
    int c = hist[b];
    hist[b] = c ? atomicAdd(&gcur[b], c) : 0;
  }
  __syncthreads();
#pragma unroll
  for (int k = 0; k < 16; ++k) {
    int i = base + tid + k * 256;
    if (i < nnz) {
      int e = edges[i], v = vertex[i];
      int pe = atomicAdd(&hist[e >> 8], 1);
      S[pe] = ((e & 255) << 17) | v;
      int pv = atomicAdd(&hist[NBE + (v >> 8)], 1);
      S[pv] = ((v & 255) << 17) | e;
    }
  }
}

// ---------------- K3: per-bucket LDS counting sort -> LE/LV, O ----------------
// edge buckets  -> LE (int32 vertex ids), O[0..NE]
// vertex buckets-> LV (u16 edge ids), O[NE+1 .. NE+1+NN]  (disjoint; no shared
//                  boundary slot — the old shared O[NE] was a write race once
//                  vertex offsets were rebased to 0 for the split LV array)
__global__ __launch_bounds__(256) void k_pass2(const int* __restrict__ gcur,
                                               const int* __restrict__ S,
                                               int* __restrict__ LE,
                                               unsigned short* __restrict__ LV,
                                               int* __restrict__ O, int nnz) {
  __shared__ int offs[257];
  __shared__ int cur[256];
  __shared__ int scratch[CAP_E];
  const int g = blockIdx.x;
  const int tid = threadIdx.x;
  // inline exclusive prefix over buckets < g
  int part = 0;
  for (int i = tid; i < g; i += 256) part += gcur[i] - bucket_base(i);
  cur[tid] = part;
  __syncthreads();
#pragma unroll
  for (int s2 = 128; s2 > 0; s2 >>= 1) {
    if (tid < s2) cur[tid] += cur[tid + s2];
    __syncthreads();
  }
  const bool isE = g < NBE;
  const int dbase = isE ? cur[0] : cur[0] - nnz;  // vertex part indexes LV from 0
  __syncthreads();

  const int sstart = bucket_base(g);
  int nit = gcur[g] - sstart;
  const int cap = isE ? CAP_E : CAP_V;
  if (nit > cap) nit = cap;  // safety clamp
  const int s0 = isE ? (g << 8) : ((g - NBE) << 8);
  const int segN = min(256, (isE ? NE : NN) - s0);
  const int obase = isE ? s0 : NE + 1 + s0;   // vertex region shifted by +1
  for (int k = tid; k < 257; k += 256) offs[k] = 0;
  __syncthreads();
  for (int t = tid; t < nit; t += 256) atomicAdd(&offs[(S[sstart + t] >> 17) + 1], 1);
  __syncthreads();
  for (int off = 1; off < 256; off <<= 1) {
    int y = (tid >= off) ? offs[tid + 1 - off] : 0;
    __syncthreads();
    offs[tid + 1] += y;
    __syncthreads();
  }
  cur[tid] = offs[tid];
  __syncthreads();
  for (int t = tid; t < nit; t += 256) {
    int u = S[sstart + t];
    int r = atomicAdd(&cur[u >> 17], 1);
    scratch[r] = u & 0x1FFFF;
  }
  __syncthreads();
  if (isE) {
    for (int t = tid; t < nit; t += 256) LE[dbase + t] = scratch[t];
  } else {
    for (int t = tid; t < nit; t += 256) LV[dbase + t] = (unsigned short)scratch[t];
  }
  for (int k = tid; k <= segN; k += 256) O[obase + k] = dbase + offs[k];
}

// ---------------- K5: Xe chunk = sum of Xb chunk rows; chunk = blockIdx.y ----------------
// gather slice per pass: NN*64B = 6.4 MB (mostly L2-resident)
__global__ __launch_bounds__(256) void k_edge_agg(const unsigned* __restrict__ Xb2c,
                                                  const int* __restrict__ O,
                                                  const int* __restrict__ LE,
                                                  unsigned* __restrict__ Xe2c) {
  const int c = blockIdx.y;                        // feature chunk 0..3
  const int e = blockIdx.x * 4 + (threadIdx.x >> 6);
  const int lane = threadIdx.x & 63;
  const int q = lane >> 4;    // quarter 0..3 (row stream)
  const int ql = lane & 15;   // 16 lanes x 4 B = 64 B chunk row
  const int start = O[e];
  const int end = O[e + 1];
  const unsigned* __restrict__ P = Xb2c + (size_t)c * NN * 16;  // uint units
  v2f a = (v2f)(0.f);
  int j = start + q;
  for (; j + 12 < end; j += 16) {
    unsigned u0 = P[(size_t)LE[j] * 16 + ql];
    unsigned u1 = P[(size_t)LE[j + 4] * 16 + ql];
    unsigned u2 = P[(size_t)LE[j + 8] * 16 + ql];
    unsigned u3 = P[(size_t)LE[j + 12] * 16 + ql];
    acc2(a, u0); acc2(a, u1); acc2(a, u2); acc2(a, u3);
  }
  if (j + 4 < end) {
    unsigned u0 = P[(size_t)LE[j] * 16 + ql];
    unsigned u1 = P[(size_t)LE[j + 4] * 16 + ql];
    acc2(a, u0); acc2(a, u1);
    j += 8;
  }
  if (j < end) {
    acc2(a, P[(size_t)LE[j] * 16 + ql]);
  }
  a.x += __shfl_xor(a.x, 16); a.x += __shfl_xor(a.x, 32);
  a.y += __shfl_xor(a.y, 16); a.y += __shfl_xor(a.y, 32);
  if (q == 0) {
    Xe2c[((size_t)c * NE + e) * 16 + ql] = pack_bf16x2(a.x, a.y);
  }
}

// ---------------- K6: out chunk = gelu((1+eps)*Xb chunk + sum Xe chunk rows) ----------------
// gather slice per pass: NE*64B = 3.2 MB -> fits per-XCD L2
__global__ __launch_bounds__(256) void k_vert_agg(const unsigned* __restrict__ Xe2c,
                                                  const int* __restrict__ O,
                                                  const unsigned short* __restrict__ LV,
                                                  const float* __restrict__ eps,
                                                  const unsigned* __restrict__ Xb2c,
                                                  float* __restrict__ out) {
  const int c = blockIdx.y;                        // feature chunk 0..3
  const int v = blockIdx.x * 4 + (threadIdx.x >> 6);
  const int lane = threadIdx.x & 63;
  const int q = lane >> 4;
  const int ql = lane & 15;
  const int start = O[NE + 1 + v];
  const int end = O[NE + 2 + v];
  const unsigned* __restrict__ Q = Xe2c + (size_t)c * NE * 16;  // uint units
  v2f a = (v2f)(0.f);
  int j = start + q;
  for (; j + 12 < end; j += 16) {
    unsigned u0 = Q[(size_t)LV[j] * 16 + ql];
    unsigned u1 = Q[(size_t)LV[j + 4] * 16 + ql];
    unsigned u2 = Q[(size_t)LV[j + 8] * 16 + ql];
    unsigned u3 = Q[(size_t)LV[j + 12] * 16 + ql];
    acc2(a, u0); acc2(a, u1); acc2(a, u2); acc2(a, u3);
  }
  if (j + 4 < end) {
    unsigned u0 = Q[(size_t)LV[j] * 16 + ql];
    unsigned u1 = Q[(size_t)LV[j + 4] * 16 + ql];
    acc2(a, u0); acc2(a, u1);
    j += 8;
  }
  if (j < end) {
    acc2(a, Q[(size_t)LV[j] * 16 + ql]);
  }
  a.x += __shfl_xor(a.x, 16); a.x += __shfl_xor(a.x, 32);
  a.y += __shfl_xor(a.y, 16); a.y += __shfl_xor(a.y, 32);
  if (q == 0) {
    // self term: chunk-major bf16 projection, streaming (nontemporal)
    unsigned su = __builtin_nontemporal_load(&Xb2c[((size_t)c * NN + v) * 16 + ql]);
    union { unsigned i; float f; } plo, phi;
    plo.i = su << 16;
    phi.i = su & 0xFFFF0000u;
    const float sc = 1.0f + eps[0];
    v2f x;
    x.x = gelu_exact(fmaf(sc, plo.f, a.x));
    x.y = gelu_exact(fmaf(sc, phi.f, a.y));
    // out[v*128 + c*32 + 2*ql + {0,1}]  (row-major fp32 output)
    v2f* __restrict__ P2 = (v2f*)out;
    __builtin_nontemporal_store(x, &P2[(size_t)v * 64 + c * 16 + ql]);
  }
}

extern "C" void kernel_launch(void* const* d_in, const int* in_sizes, int n_in,
                              void* d_out, int out_size, void* d_ws, size_t ws_size,
                              hipStream_t stream) {
  const float* X = (const float*)d_in[0];
  const float* W = (const float*)d_in[1];
  const float* eps = (const float*)d_in[2];
  const int* vertex = (const int*)d_in[3];
  const int* edges = (const int*)d_in[4];
  const int nnz = in_sizes[3];

  // workspace layout. CSR build runs BEFORE the GEMM, so staging S aliases Xb2c.
  char* ws = (char*)d_ws;
  size_t off = 0;
  auto alloc = [&](size_t bytes) -> void* {
    void* p = ws + off;
    off = (off + bytes + 255) & ~(size_t)255;
    return p;
  };
  const size_t stagingB = ((size_t)NBE * CAP_E + (size_t)NBV * CAP_V) * 4;  // ~14.2 MB
  const size_t xbB = (size_t)NN * DD * 2;                                   // 25.6 MB
  void* A = alloc(xbB > stagingB ? xbB : stagingB);
  int* S = (int*)A;                          // staging slabs (dead after k_pass2)
  unsigned short* Xb2c = (unsigned short*)A;  // chunk-major bf16 Xp (born in k_gemm)
  unsigned* Xe2c = (unsigned*)alloc((size_t)NE * DD * 2);   // 12.8 MB chunk-major bf16 Xe
  int* LE = (int*)alloc((size_t)nnz * sizeof(int));         // 6.4 MB (vertex ids)
  unsigned short* LV =
      (unsigned short*)alloc((size_t)nnz * sizeof(unsigned short));  // 3.2 MB (edge ids)
  int* O = (int*)alloc((size_t)(NSEG + 2) * sizeof(int));   // 0.6 MB (disjoint E/V regions)
  int* gcur = (int*)alloc((size_t)NB * sizeof(int));
  unsigned short* Wt = (unsigned short*)alloc((size_t)DD * DD * 2);  // 32 KB bf16 W^T
  if (off > ws_size) return;

  k_init<<<67, 256, 0, stream>>>(gcur, W, Wt);
  k_pass1<<<(nnz + 4095) / 4096, 256, 0, stream>>>(vertex, edges, gcur, S, nnz);
  k_pass2<<<NB, 256, 0, stream>>>(gcur, S, LE, LV, O, nnz);
  k_gemm<<<(NN + 63) / 64, 256, 0, stream>>>(X, Wt, Xb2c);
  k_edge_agg<<<dim3(NE / 4, 4), 256, 0, stream>>>((const unsigned*)Xb2c, O, LE, Xe2c);
  k_vert_agg<<<dim3(NN / 4, 4), 256, 0, stream>>>(Xe2c, O, LV, eps,
                                                  (const unsigned*)Xb2c, (float*)d_out);
}

// Round 7
// 347.556 us; speedup vs baseline: 1.2304x; 1.2304x over previous
//
#include <hip/hip_runtime.h>
#include <math.h>

#define NN 100000   // nodes
#define NE 50000    // edges (segments of first aggregate)
#define NSEG (NE + NN)
#define DD 128      // feature dim

// bucketing for the binned CSR build: bucket = id >> 8 (256 segments/bucket)
#define NBE 196                 // ceil(50000/256)
#define NBV 391                 // ceil(100000/256)
#define NB  (NBE + NBV)         // 587
#define CAP_E 8960              // slab cap per edge bucket (mean 8192, sigma~90)
#define CAP_V 4608              // slab cap per vertex bucket (mean 4096, sigma~64)

typedef short bf16x8 __attribute__((ext_vector_type(8)));
typedef float f32x4 __attribute__((ext_vector_type(4)));
typedef float v2f __attribute__((ext_vector_type(2)));

static __device__ __forceinline__ float gelu_exact(float x) {
  return 0.5f * x * (1.0f + erff(x * 0.70710678118654752f));
}

static __device__ __forceinline__ int bucket_base(int g) {
  return (g < NBE) ? g * CAP_E : NBE * CAP_E + (g - NBE) * CAP_V;
}

// unpack 2 bf16 from a uint and accumulate into a float2 (v_pk_add_f32)
static __device__ __forceinline__ void acc2(v2f& a, unsigned u) {
  union { unsigned i; float f; } lo, hi;
  lo.i = u << 16;
  hi.i = u & 0xFFFF0000u;
  v2f t;
  t.x = lo.f;
  t.y = hi.f;
  a += t;
}

static __device__ __forceinline__ void acc4(v2f* a, uint4 u) {
  acc2(a[0], u.x); acc2(a[1], u.y); acc2(a[2], u.z); acc2(a[3], u.w);
}

// pack 2 fp32 -> bf16x2 (round to nearest even)
static __device__ __forceinline__ unsigned pack_bf16x2(float a, float b) {
  unsigned ua = __float_as_uint(a), ub = __float_as_uint(b);
  ua = (ua + 0x7FFFu + ((ua >> 16) & 1u)) >> 16;
  ub = (ub + 0x7FFFu + ((ub >> 16) & 1u)) >> 16;
  return ua | (ub << 16);
}

static __device__ __forceinline__ unsigned short bf16_rne(float a) {
  unsigned ua = __float_as_uint(a);
  ua = (ua + 0x7FFFu + ((ua >> 16) & 1u)) >> 16;
  return (unsigned short)ua;
}

// reduce across the 8 streams (lane = s*8 + r; xor on bits 3..5 reduces over s)
static __device__ __forceinline__ void reduce8(v2f* a) {
#pragma unroll
  for (int k = 0; k < 4; ++k) {
    float x = a[k].x, y = a[k].y;
    x += __shfl_xor(x, 8);  y += __shfl_xor(y, 8);
    x += __shfl_xor(x, 16); y += __shfl_xor(y, 16);
    x += __shfl_xor(x, 32); y += __shfl_xor(y, 32);
    a[k].x = x; a[k].y = y;
  }
}

// ---------------- K0: init bucket cursors + Wt[n][k] = bf16(W[k][n]) ----------------
__global__ __launch_bounds__(256) void k_init(int* __restrict__ gcur,
                                              const float* __restrict__ W,
                                              unsigned short* __restrict__ Wt) {
  const int b = blockIdx.x;
  if (b < 64) {
    int idx = b * 256 + threadIdx.x;  // 16384 = 128*128
    int k = idx >> 7, n = idx & 127;
    Wt[n * 128 + k] = bf16_rne(W[idx]);
  } else {
    int g = (b - 64) * 256 + threadIdx.x;
    if (g < NB) gcur[g] = bucket_base(g);
  }
}

// ---------------- K1: Xp = X @ W via bf16 MFMA; writes 2-CHUNK-MAJOR bf16 ----------------
// Xb2h layout: [2 halves][NN][64 bf16]  (half h holds feature cols [64h, 64h+64))
__global__ __launch_bounds__(256) void k_gemm(const float* __restrict__ X,
                                              const unsigned short* __restrict__ Wt,
                                              unsigned short* __restrict__ Xb2h) {
  const int tid = threadIdx.x;
  const int w = tid >> 6;          // wave 0..3
  const int l = tid & 63;
  const int lm = l & 15;           // A row / B col within tile
  const int lk = l >> 4;           // k-group 0..3
  const int R = blockIdx.x * 64 + w * 16;
  const int arow = R + lm;
  const bool rowok = arow < NN;
  const f32x4* __restrict__ X4 = (const f32x4*)X;
  const uint4* __restrict__ Wt4 = (const uint4*)Wt;

  f32x4 acc[8];
#pragma unroll
  for (int t = 0; t < 8; ++t) acc[t] = (f32x4)(0.f);

  for (int c = 0; c < 4; ++c) {
    const int k0 = c * 32 + lk * 8;
    f32x4 x0 = (f32x4)(0.f), x1 = (f32x4)(0.f);
    if (rowok) {
      x0 = __builtin_nontemporal_load(&X4[arow * 32 + (k0 >> 2)]);
      x1 = __builtin_nontemporal_load(&X4[arow * 32 + (k0 >> 2) + 1]);
    }
    union { bf16x8 v; uint4 u; } a;
    a.u.x = pack_bf16x2(x0.x, x0.y);
    a.u.y = pack_bf16x2(x0.z, x0.w);
    a.u.z = pack_bf16x2(x1.x, x1.y);
    a.u.w = pack_bf16x2(x1.z, x1.w);
#pragma unroll
    for (int t = 0; t < 8; ++t) {
      union { bf16x8 v; uint4 u; } b;
      b.u = Wt4[(t * 16 + lm) * 16 + c * 4 + lk];  // 8 bf16 = 16B, k-contiguous
      acc[t] = __builtin_amdgcn_mfma_f32_16x16x32_bf16(a.v, b.v, acc[t], 0, 0, 0);
    }
  }

  const int drow = R + lk * 4;
#pragma unroll
  for (int r = 0; r < 4; ++r) {
    const int row = drow + r;
    if (row < NN) {
#pragma unroll
      for (int t = 0; t < 8; ++t) {
        // col = t*16+lm; half = t>>2; within-half ushort = (t&3)*16 + lm
        __builtin_nontemporal_store(
            bf16_rne(acc[t][r]),
            &Xb2h[((size_t)(t >> 2) * NN + row) * 64 + (t & 3) * 16 + lm]);
      }
    }
  }
}

// ---------------- K2: bin incidences into bucket slabs ----------------
// staged item: (seg & 255) << 17 | value  (both values < 2^17)
__global__ __launch_bounds__(256) void k_pass1(const int* __restrict__ vertex,
                                               const int* __restrict__ edges,
                                               int* __restrict__ gcur,
                                               int* __restrict__ S, int nnz) {
  __shared__ int hist[NB];
  const int tid = threadIdx.x;
  for (int b = tid; b < NB; b += 256) hist[b] = 0;
  __syncthreads();
  const int base = blockIdx.x * 4096;
#pragma unroll
  for (int k = 0; k < 16; ++k) {
    int i = base + tid + k * 256;
    if (i < nnz) {
      atomicAdd(&hist[edges[i] >> 8], 1);
      atomicAdd(&hist[NBE + (vertex[i] >> 8)], 1);
    }
  }
  __syncthreads();
  for (int b = tid; b < NB; b += 256) {
    int c = hist[b];
    hist[b] = c ? atomicAdd(&gcur[b], c) : 0;
  }
  __syncthreads();
#pragma unroll
  for (int k = 0; k < 16; ++k) {
    int i = base + tid + k * 256;
    if (i < nnz) {
      int e = edges[i], v = vertex[i];
      int pe = atomicAdd(&hist[e >> 8], 1);
      S[pe] = ((e & 255) << 17) | v;
      int pv = atomicAdd(&hist[NBE + (v >> 8)], 1);
      S[pv] = ((v & 255) << 17) | e;
    }
  }
}

// ---------------- K3: per-bucket LDS counting sort -> LE/LV, O ----------------
// edge buckets  -> LE (int32 vertex ids), O[0..NE]
// vertex buckets-> LV (u16 edge ids), O[NE+1 .. NE+1+NN]  (disjoint regions)
__global__ __launch_bounds__(256) void k_pass2(const int* __restrict__ gcur,
                                               const int* __restrict__ S,
                                               int* __restrict__ LE,
                                               unsigned short* __restrict__ LV,
                                               int* __restrict__ O, int nnz) {
  __shared__ int offs[257];
  __shared__ int cur[256];
  __shared__ int scratch[CAP_E];
  const int g = blockIdx.x;
  const int tid = threadIdx.x;
  // inline exclusive prefix over buckets < g
  int part = 0;
  for (int i = tid; i < g; i += 256) part += gcur[i] - bucket_base(i);
  cur[tid] = part;
  __syncthreads();
#pragma unroll
  for (int s2 = 128; s2 > 0; s2 >>= 1) {
    if (tid < s2) cur[tid] += cur[tid + s2];
    __syncthreads();
  }
  const bool isE = g < NBE;
  const int dbase = isE ? cur[0] : cur[0] - nnz;  // vertex part indexes LV from 0
  __syncthreads();

  const int sstart = bucket_base(g);
  int nit = gcur[g] - sstart;
  const int cap = isE ? CAP_E : CAP_V;
  if (nit > cap) nit = cap;  // safety clamp
  const int s0 = isE ? (g << 8) : ((g - NBE) << 8);
  const int segN = min(256, (isE ? NE : NN) - s0);
  const int obase = isE ? s0 : NE + 1 + s0;   // vertex region shifted by +1
  for (int k = tid; k < 257; k += 256) offs[k] = 0;
  __syncthreads();
  for (int t = tid; t < nit; t += 256) atomicAdd(&offs[(S[sstart + t] >> 17) + 1], 1);
  __syncthreads();
  for (int off = 1; off < 256; off <<= 1) {
    int y = (tid >= off) ? offs[tid + 1 - off] : 0;
    __syncthreads();
    offs[tid + 1] += y;
    __syncthreads();
  }
  cur[tid] = offs[tid];
  __syncthreads();
  for (int t = tid; t < nit; t += 256) {
    int u = S[sstart + t];
    int r = atomicAdd(&cur[u >> 17], 1);
    scratch[r] = u & 0x1FFFF;
  }
  __syncthreads();
  if (isE) {
    for (int t = tid; t < nit; t += 256) LE[dbase + t] = scratch[t];
  } else {
    for (int t = tid; t < nit; t += 256) LV[dbase + t] = (unsigned short)scratch[t];
  }
  for (int k = tid; k <= segN; k += 256) O[obase + k] = dbase + offs[k];
}

// ---------------- K5: Xe half = sum of Xb half rows; half = blockIdx.y ----------------
// 8 streams x 8 lanes x 16B per wave; gather slice per pass: NN*128B = 12.8 MB
__global__ __launch_bounds__(256) void k_edge_agg(const unsigned* __restrict__ Xb2h,
                                                  const int* __restrict__ O,
                                                  const int* __restrict__ LE,
                                                  unsigned* __restrict__ Xe2h) {
  const int h = blockIdx.y;                        // feature half 0..1
  const int e = blockIdx.x * 4 + (threadIdx.x >> 6);
  const int lane = threadIdx.x & 63;
  const int s = lane >> 3;    // stream 0..7
  const int r = lane & 7;     // 8 lanes x 16 B = 128 B half-row
  const int start = O[e];
  const int end = O[e + 1];
  const uint4* __restrict__ P = (const uint4*)(Xb2h + (size_t)h * NN * 32);  // row=8 uint4
  v2f a[4];
#pragma unroll
  for (int k = 0; k < 4; ++k) a[k] = (v2f)(0.f);
  int j = start + s;
  for (; j + 24 < end; j += 32) {   // 4-deep (mean edge deg = 32)
    int i0 = __builtin_nontemporal_load(&LE[j]);
    int i1 = __builtin_nontemporal_load(&LE[j + 8]);
    int i2 = __builtin_nontemporal_load(&LE[j + 16]);
    int i3 = __builtin_nontemporal_load(&LE[j + 24]);
    uint4 u0 = P[(size_t)i0 * 8 + r];
    uint4 u1 = P[(size_t)i1 * 8 + r];
    uint4 u2 = P[(size_t)i2 * 8 + r];
    uint4 u3 = P[(size_t)i3 * 8 + r];
    acc4(a, u0); acc4(a, u1); acc4(a, u2); acc4(a, u3);
  }
  if (j + 8 < end) {
    int i0 = __builtin_nontemporal_load(&LE[j]);
    int i1 = __builtin_nontemporal_load(&LE[j + 8]);
    uint4 u0 = P[(size_t)i0 * 8 + r];
    uint4 u1 = P[(size_t)i1 * 8 + r];
    acc4(a, u0); acc4(a, u1);
    j += 16;
  }
  if (j < end) {
    int i0 = __builtin_nontemporal_load(&LE[j]);
    acc4(a, P[(size_t)i0 * 8 + r]);
  }
  reduce8(a);
  // all lanes hold full sums for their r; lane (s<4) stores pair p=s
  const int p = s & 3;
  v2f sel = (p == 0) ? a[0] : (p == 1) ? a[1] : (p == 2) ? a[2] : a[3];
  unsigned pk = pack_bf16x2(sel.x, sel.y);
  if (s < 4) {
    // uint index within 32-uint half-row: r*4 + p
    __builtin_nontemporal_store(pk, &Xe2h[((size_t)h * NE + e) * 32 + r * 4 + p]);
  }
}

// ---------------- K6: out half = gelu((1+eps)*Xb half + sum Xe half rows) ----------------
// gather slice per pass: NE*128B = 6.4 MB
__global__ __launch_bounds__(256) void k_vert_agg(const unsigned* __restrict__ Xe2h,
                                                  const int* __restrict__ O,
                                                  const unsigned short* __restrict__ LV,
                                                  const float* __restrict__ eps,
                                                  const unsigned* __restrict__ Xb2h,
                                                  float* __restrict__ out) {
  const int h = blockIdx.y;                        // feature half 0..1
  const int v = blockIdx.x * 4 + (threadIdx.x >> 6);
  const int lane = threadIdx.x & 63;
  const int s = lane >> 3;
  const int r = lane & 7;
  const int start = O[NE + 1 + v];
  const int end = O[NE + 2 + v];
  const uint4* __restrict__ Q = (const uint4*)(Xe2h + (size_t)h * NE * 32);
  v2f a[4];
#pragma unroll
  for (int k = 0; k < 4; ++k) a[k] = (v2f)(0.f);
  int j = start + s;
  for (; j + 8 < end; j += 16) {    // 2-deep (mean vertex deg = 16)
    int i0 = (int)__builtin_nontemporal_load(&LV[j]);
    int i1 = (int)__builtin_nontemporal_load(&LV[j + 8]);
    uint4 u0 = Q[(size_t)i0 * 8 + r];
    uint4 u1 = Q[(size_t)i1 * 8 + r];
    acc4(a, u0); acc4(a, u1);
  }
  if (j < end) {
    int i0 = (int)__builtin_nontemporal_load(&LV[j]);
    acc4(a, Q[(size_t)i0 * 8 + r]);
  }
  reduce8(a);
  // all-lane epilogue: lane (s,r) handles feature pair p = s&3 of its r-quad
  const int p = s & 3;
  v2f sel = (p == 0) ? a[0] : (p == 1) ? a[1] : (p == 2) ? a[2] : a[3];
  // self term: uint (r*4+p) of the 32-uint half-row v
  unsigned su = __builtin_nontemporal_load(&Xb2h[((size_t)h * NN + v) * 32 + r * 4 + p]);
  union { unsigned i; float f; } plo, phi;
  plo.i = su << 16;
  phi.i = su & 0xFFFF0000u;
  const float sc = 1.0f + eps[0];
  v2f x;
  x.x = gelu_exact(fmaf(sc, plo.f, sel.x));
  x.y = gelu_exact(fmaf(sc, phi.f, sel.y));
  if (s < 4) {
    // float2 index within row: h*32 + r*4 + p
    v2f* __restrict__ P2 = (v2f*)out;
    __builtin_nontemporal_store(x, &P2[(size_t)v * 64 + h * 32 + r * 4 + p]);
  }
}

extern "C" void kernel_launch(void* const* d_in, const int* in_sizes, int n_in,
                              void* d_out, int out_size, void* d_ws, size_t ws_size,
                              hipStream_t stream) {
  const float* X = (const float*)d_in[0];
  const float* W = (const float*)d_in[1];
  const float* eps = (const float*)d_in[2];
  const int* vertex = (const int*)d_in[3];
  const int* edges = (const int*)d_in[4];
  const int nnz = in_sizes[3];

  // workspace layout. CSR build runs BEFORE the GEMM, so staging S aliases Xb2h.
  char* ws = (char*)d_ws;
  size_t off = 0;
  auto alloc = [&](size_t bytes) -> void* {
    void* p = ws + off;
    off = (off + bytes + 255) & ~(size_t)255;
    return p;
  };
  const size_t stagingB = ((size_t)NBE * CAP_E + (size_t)NBV * CAP_V) * 4;  // ~14.2 MB
  const size_t xbB = (size_t)NN * DD * 2;                                   // 25.6 MB
  void* A = alloc(xbB > stagingB ? xbB : stagingB);
  int* S = (int*)A;                           // staging slabs (dead after k_pass2)
  unsigned short* Xb2h = (unsigned short*)A;  // 2-half-major bf16 Xp (born in k_gemm)
  unsigned* Xe2h = (unsigned*)alloc((size_t)NE * DD * 2);   // 12.8 MB half-major bf16 Xe
  int* LE = (int*)alloc((size_t)nnz * sizeof(int));         // 6.4 MB (vertex ids)
  unsigned short* LV =
      (unsigned short*)alloc((size_t)nnz * sizeof(unsigned short));  // 3.2 MB (edge ids)
  int* O = (int*)alloc((size_t)(NSEG + 2) * sizeof(int));   // disjoint E/V regions
  int* gcur = (int*)alloc((size_t)NB * sizeof(int));
  unsigned short* Wt = (unsigned short*)alloc((size_t)DD * DD * 2);  // 32 KB bf16 W^T
  if (off > ws_size) return;

  k_init<<<67, 256, 0, stream>>>(gcur, W, Wt);
  k_pass1<<<(nnz + 4095) / 4096, 256, 0, stream>>>(vertex, edges, gcur, S, nnz);
  k_pass2<<<NB, 256, 0, stream>>>(gcur, S, LE, LV, O, nnz);
  k_gemm<<<(NN + 63) / 64, 256, 0, stream>>>(X, Wt, Xb2h);
  k_edge_agg<<<dim3(NE / 4, 2), 256, 0, stream>>>((const unsigned*)Xb2h, O, LE, Xe2h);
  k_vert_agg<<<dim3(NN / 4, 2), 256, 0, stream>>>(Xe2h, O, LV, eps,
                                                  (const unsigned*)Xb2h, (float*)d_out);
}

// Round 8
// 314.901 us; speedup vs baseline: 1.3580x; 1.1037x over previous
//
#include <hip/hip_runtime.h>
#include <math.h>

#define NN 100000   // nodes
#define NE 50000    // edges (segments of first aggregate)
#define NSEG (NE + NN)
#define DD 128      // feature dim

// bucketing for the binned CSR build: bucket = id >> 8 (256 segments/bucket)
#define NBE 196                 // ceil(50000/256)
#define NBV 391                 // ceil(100000/256)
#define NB  (NBE + NBV)         // 587
#define CAP_E 8960              // slab cap per edge bucket (mean 8192, sigma~90)
#define CAP_V 4608              // slab cap per vertex bucket (mean 4096, sigma~64)

typedef short bf16x8 __attribute__((ext_vector_type(8)));
typedef float f32x4 __attribute__((ext_vector_type(4)));
typedef float v2f __attribute__((ext_vector_type(2)));

static __device__ __forceinline__ float gelu_exact(float x) {
  return 0.5f * x * (1.0f + erff(x * 0.70710678118654752f));
}

static __device__ __forceinline__ int bucket_base(int g) {
  return (g < NBE) ? g * CAP_E : NBE * CAP_E + (g - NBE) * CAP_V;
}

// unpack 2 bf16 from a uint and accumulate into a float2 (v_pk_add_f32)
static __device__ __forceinline__ void acc2(v2f& a, unsigned u) {
  union { unsigned i; float f; } lo, hi;
  lo.i = u << 16;
  hi.i = u & 0xFFFF0000u;
  v2f t;
  t.x = lo.f;
  t.y = hi.f;
  a += t;
}

static __device__ __forceinline__ void acc4(v2f* a, uint4 u) {
  acc2(a[0], u.x); acc2(a[1], u.y); acc2(a[2], u.z); acc2(a[3], u.w);
}

// pack 2 fp32 -> bf16x2 (round to nearest even)
static __device__ __forceinline__ unsigned pack_bf16x2(float a, float b) {
  unsigned ua = __float_as_uint(a), ub = __float_as_uint(b);
  ua = (ua + 0x7FFFu + ((ua >> 16) & 1u)) >> 16;
  ub = (ub + 0x7FFFu + ((ub >> 16) & 1u)) >> 16;
  return ua | (ub << 16);
}

static __device__ __forceinline__ unsigned short bf16_rne(float a) {
  unsigned ua = __float_as_uint(a);
  ua = (ua + 0x7FFFu + ((ua >> 16) & 1u)) >> 16;
  return (unsigned short)ua;
}

// reduce over the 4 row-streams (lane = q*16 + ql)
static __device__ __forceinline__ void reduce4(v2f* a) {
#pragma unroll
  for (int k = 0; k < 4; ++k) {
    float x = a[k].x, y = a[k].y;
    x += __shfl_xor(x, 16); y += __shfl_xor(y, 16);
    x += __shfl_xor(x, 32); y += __shfl_xor(y, 32);
    a[k].x = x; a[k].y = y;
  }
}

// ---------------- K0: init bucket cursors + Wt[n][k] = bf16(W[k][n]) ----------------
__global__ __launch_bounds__(256) void k_init(int* __restrict__ gcur,
                                              const float* __restrict__ W,
                                              unsigned short* __restrict__ Wt) {
  const int b = blockIdx.x;
  if (b < 64) {
    int idx = b * 256 + threadIdx.x;  // 16384 = 128*128
    int k = idx >> 7, n = idx & 127;
    Wt[n * 128 + k] = bf16_rne(W[idx]);
  } else {
    int g = (b - 64) * 256 + threadIdx.x;
    if (g < NB) gcur[g] = bucket_base(g);
  }
}

// ---------------- K1: Xp = X @ W via bf16 MFMA; writes ROW-MAJOR bf16 ----------------
// mfma_f32_16x16x32_bf16: A lane l holds A[m][k], m=l&15, k=(l>>4)*8+e;
// B lane l holds B[k][n], n=l&15; C/D lane l reg r = D[(l>>4)*4+r][l&15]
__global__ __launch_bounds__(256) void k_gemm(const float* __restrict__ X,
                                              const unsigned short* __restrict__ Wt,
                                              unsigned short* __restrict__ Xb2) {
  const int tid = threadIdx.x;
  const int w = tid >> 6;          // wave 0..3
  const int l = tid & 63;
  const int lm = l & 15;           // A row / B col within tile
  const int lk = l >> 4;           // k-group 0..3
  const int R = blockIdx.x * 64 + w * 16;
  const int arow = R + lm;
  const bool rowok = arow < NN;
  const f32x4* __restrict__ X4 = (const f32x4*)X;
  const uint4* __restrict__ Wt4 = (const uint4*)Wt;

  f32x4 acc[8];
#pragma unroll
  for (int t = 0; t < 8; ++t) acc[t] = (f32x4)(0.f);

  for (int c = 0; c < 4; ++c) {
    const int k0 = c * 32 + lk * 8;
    f32x4 x0 = (f32x4)(0.f), x1 = (f32x4)(0.f);
    if (rowok) {
      x0 = __builtin_nontemporal_load(&X4[arow * 32 + (k0 >> 2)]);
      x1 = __builtin_nontemporal_load(&X4[arow * 32 + (k0 >> 2) + 1]);
    }
    union { bf16x8 v; uint4 u; } a;
    a.u.x = pack_bf16x2(x0.x, x0.y);
    a.u.y = pack_bf16x2(x0.z, x0.w);
    a.u.z = pack_bf16x2(x1.x, x1.y);
    a.u.w = pack_bf16x2(x1.z, x1.w);
#pragma unroll
    for (int t = 0; t < 8; ++t) {
      union { bf16x8 v; uint4 u; } b;
      b.u = Wt4[(t * 16 + lm) * 16 + c * 4 + lk];  // 8 bf16 = 16B, k-contiguous
      acc[t] = __builtin_amdgcn_mfma_f32_16x16x32_bf16(a.v, b.v, acc[t], 0, 0, 0);
    }
  }

  const int drow = R + lk * 4;
#pragma unroll
  for (int r = 0; r < 4; ++r) {
    const int row = drow + r;
    if (row < NN) {
#pragma unroll
      for (int t = 0; t < 8; ++t) {
        Xb2[row * 128 + t * 16 + lm] = bf16_rne(acc[t][r]);
      }
    }
  }
}

// ---------------- K2: bin incidences into bucket slabs ----------------
// staged item: (seg & 255) << 17 | value  (both values < 2^17)
__global__ __launch_bounds__(256) void k_pass1(const int* __restrict__ vertex,
                                               const int* __restrict__ edges,
                                               int* __restrict__ gcur,
                                               int* __restrict__ S, int nnz) {
  __shared__ int hist[NB];
  const int tid = threadIdx.x;
  for (int b = tid; b < NB; b += 256) hist[b] = 0;
  __syncthreads();
  const int base = blockIdx.x * 4096;
#pragma unroll
  for (int k = 0; k < 16; ++k) {
    int i = base + tid + k * 256;
    if (i < nnz) {
      atomicAdd(&hist[edges[i] >> 8], 1);
      atomicAdd(&hist[NBE + (vertex[i] >> 8)], 1);
    }
  }
  __syncthreads();
  for (int b = tid; b < NB; b += 256) {
    int c = hist[b];
    hist[b] = c ? atomicAdd(&gcur[b], c) : 0;
  }
  __syncthreads();
#pragma unroll
  for (int k = 0; k < 16; ++k) {
    int i = base + tid + k * 256;
    if (i < nnz) {
      int e = edges[i], v = vertex[i];
      int pe = atomicAdd(&hist[e >> 8], 1);
      S[pe] = ((e & 255) << 17) | v;
      int pv = atomicAdd(&hist[NBE + (v >> 8)], 1);
      S[pv] = ((v & 255) << 17) | e;
    }
  }
}

// ---------------- K3: per-bucket LDS counting sort -> LE/LV, O ----------------
// edge buckets  -> LE (int32 vertex ids), O[0..NE]
// vertex buckets-> LV (u16 edge ids), O[NE+1 .. NE+1+NN]  (disjoint regions)
__global__ __launch_bounds__(256) void k_pass2(const int* __restrict__ gcur,
                                               const int* __restrict__ S,
                                               int* __restrict__ LE,
                                               unsigned short* __restrict__ LV,
                                               int* __restrict__ O, int nnz) {
  __shared__ int offs[257];
  __shared__ int cur[256];
  __shared__ int scratch[CAP_E];
  const int g = blockIdx.x;
  const int tid = threadIdx.x;
  // inline exclusive prefix over buckets < g
  int part = 0;
  for (int i = tid; i < g; i += 256) part += gcur[i] - bucket_base(i);
  cur[tid] = part;
  __syncthreads();
#pragma unroll
  for (int s2 = 128; s2 > 0; s2 >>= 1) {
    if (tid < s2) cur[tid] += cur[tid + s2];
    __syncthreads();
  }
  const bool isE = g < NBE;
  const int dbase = isE ? cur[0] : cur[0] - nnz;  // vertex part indexes LV from 0
  __syncthreads();

  const int sstart = bucket_base(g);
  int nit = gcur[g] - sstart;
  const int cap = isE ? CAP_E : CAP_V;
  if (nit > cap) nit = cap;  // safety clamp
  const int s0 = isE ? (g << 8) : ((g - NBE) << 8);
  const int segN = min(256, (isE ? NE : NN) - s0);
  const int obase = isE ? s0 : NE + 1 + s0;   // vertex region shifted by +1
  for (int k = tid; k < 257; k += 256) offs[k] = 0;
  __syncthreads();
  for (int t = tid; t < nit; t += 256) atomicAdd(&offs[(S[sstart + t] >> 17) + 1], 1);
  __syncthreads();
  for (int off = 1; off < 256; off <<= 1) {
    int y = (tid >= off) ? offs[tid + 1 - off] : 0;
    __syncthreads();
    offs[tid + 1] += y;
    __syncthreads();
  }
  cur[tid] = offs[tid];
  __syncthreads();
  for (int t = tid; t < nit; t += 256) {
    int u = S[sstart + t];
    int r = atomicAdd(&cur[u >> 17], 1);
    scratch[r] = u & 0x1FFFF;
  }
  __syncthreads();
  if (isE) {
    for (int t = tid; t < nit; t += 256) LE[dbase + t] = scratch[t];
  } else {
    for (int t = tid; t < nit; t += 256) LV[dbase + t] = (unsigned short)scratch[t];
  }
  for (int k = tid; k <= segN; k += 256) O[obase + k] = dbase + offs[k];
}

// ---------------- K5: Xe[e] = sum of bf16 Xp rows; 4 streams x 8-deep ----------------
__global__ __launch_bounds__(256) void k_edge_agg(const unsigned* __restrict__ Xb2,
                                                  const int* __restrict__ O,
                                                  const int* __restrict__ LE,
                                                  unsigned* __restrict__ Xe2) {
  const int e = blockIdx.x * 4 + (threadIdx.x >> 6);
  const int lane = threadIdx.x & 63;
  const int q = lane >> 4;    // row-stream 0..3
  const int ql = lane & 15;   // 16 lanes x 16 B = 256 B row
  const int start = O[e];
  const int end = O[e + 1];
  const uint4* __restrict__ P = (const uint4*)Xb2;   // row = 16 uint4
  v2f a[4];
#pragma unroll
  for (int k = 0; k < 4; ++k) a[k] = (v2f)(0.f);
  int j = start + q;
  // mean deg 32 -> 8 rows/stream: one 8-deep iteration keeps whole segment in flight
  for (; j + 28 < end; j += 32) {
    int i0 = __builtin_nontemporal_load(&LE[j]);
    int i1 = __builtin_nontemporal_load(&LE[j + 4]);
    int i2 = __builtin_nontemporal_load(&LE[j + 8]);
    int i3 = __builtin_nontemporal_load(&LE[j + 12]);
    int i4 = __builtin_nontemporal_load(&LE[j + 16]);
    int i5 = __builtin_nontemporal_load(&LE[j + 20]);
    int i6 = __builtin_nontemporal_load(&LE[j + 24]);
    int i7 = __builtin_nontemporal_load(&LE[j + 28]);
    uint4 u0 = P[(size_t)i0 * 16 + ql];
    uint4 u1 = P[(size_t)i1 * 16 + ql];
    uint4 u2 = P[(size_t)i2 * 16 + ql];
    uint4 u3 = P[(size_t)i3 * 16 + ql];
    uint4 u4 = P[(size_t)i4 * 16 + ql];
    uint4 u5 = P[(size_t)i5 * 16 + ql];
    uint4 u6 = P[(size_t)i6 * 16 + ql];
    uint4 u7 = P[(size_t)i7 * 16 + ql];
    acc4(a, u0); acc4(a, u1); acc4(a, u2); acc4(a, u3);
    acc4(a, u4); acc4(a, u5); acc4(a, u6); acc4(a, u7);
  }
  for (; j + 12 < end; j += 16) {
    int i0 = __builtin_nontemporal_load(&LE[j]);
    int i1 = __builtin_nontemporal_load(&LE[j + 4]);
    int i2 = __builtin_nontemporal_load(&LE[j + 8]);
    int i3 = __builtin_nontemporal_load(&LE[j + 12]);
    uint4 u0 = P[(size_t)i0 * 16 + ql];
    uint4 u1 = P[(size_t)i1 * 16 + ql];
    uint4 u2 = P[(size_t)i2 * 16 + ql];
    uint4 u3 = P[(size_t)i3 * 16 + ql];
    acc4(a, u0); acc4(a, u1); acc4(a, u2); acc4(a, u3);
  }
  if (j + 4 < end) {
    int i0 = __builtin_nontemporal_load(&LE[j]);
    int i1 = __builtin_nontemporal_load(&LE[j + 4]);
    uint4 u0 = P[(size_t)i0 * 16 + ql];
    uint4 u1 = P[(size_t)i1 * 16 + ql];
    acc4(a, u0); acc4(a, u1);
    j += 8;
  }
  if (j < end) {
    int i0 = __builtin_nontemporal_load(&LE[j]);
    acc4(a, P[(size_t)i0 * 16 + ql]);
  }
  reduce4(a);
  // all 64 lanes hold the full 8-feature sums; lane (q,ql) writes pair 4*ql+q
  v2f sel = (q == 0) ? a[0] : (q == 1) ? a[1] : (q == 2) ? a[2] : a[3];
  Xe2[e * 64 + ql * 4 + q] = pack_bf16x2(sel.x, sel.y);
}

// ---------------- K6: out[v] = gelu((1+eps)*bf16(Xp[v]) + sum bf16 Xe rows) ----------------
__global__ __launch_bounds__(256) void k_vert_agg(const unsigned* __restrict__ Xe2,
                                                  const int* __restrict__ O,
                                                  const unsigned short* __restrict__ LV,
                                                  const float* __restrict__ eps,
                                                  const unsigned* __restrict__ Xb2,
                                                  float* __restrict__ out) {
  const int v = blockIdx.x * 4 + (threadIdx.x >> 6);
  const int lane = threadIdx.x & 63;
  const int q = lane >> 4;
  const int ql = lane & 15;
  const int start = O[NE + 1 + v];
  const int end = O[NE + 2 + v];
  const uint4* __restrict__ Q = (const uint4*)Xe2;
  v2f a[4];
#pragma unroll
  for (int k = 0; k < 4; ++k) a[k] = (v2f)(0.f);
  int j = start + q;
  // mean deg 16 -> 4 rows/stream: one 4-deep iteration covers the typical segment
  for (; j + 12 < end; j += 16) {
    int i0 = (int)__builtin_nontemporal_load(&LV[j]);
    int i1 = (int)__builtin_nontemporal_load(&LV[j + 4]);
    int i2 = (int)__builtin_nontemporal_load(&LV[j + 8]);
    int i3 = (int)__builtin_nontemporal_load(&LV[j + 12]);
    uint4 u0 = Q[(size_t)i0 * 16 + ql];
    uint4 u1 = Q[(size_t)i1 * 16 + ql];
    uint4 u2 = Q[(size_t)i2 * 16 + ql];
    uint4 u3 = Q[(size_t)i3 * 16 + ql];
    acc4(a, u0); acc4(a, u1); acc4(a, u2); acc4(a, u3);
  }
  if (j + 4 < end) {
    int i0 = (int)__builtin_nontemporal_load(&LV[j]);
    int i1 = (int)__builtin_nontemporal_load(&LV[j + 4]);
    uint4 u0 = Q[(size_t)i0 * 16 + ql];
    uint4 u1 = Q[(size_t)i1 * 16 + ql];
    acc4(a, u0); acc4(a, u1);
    j += 8;
  }
  if (j < end) {
    int i0 = (int)__builtin_nontemporal_load(&LV[j]);
    acc4(a, Q[(size_t)i0 * 16 + ql]);
  }
  reduce4(a);
  // all-lane epilogue: lane (q,ql) owns feature pair 4*ql+q of row v
  v2f sel = (q == 0) ? a[0] : (q == 1) ? a[1] : (q == 2) ? a[2] : a[3];
  unsigned su = __builtin_nontemporal_load(&Xb2[v * 64 + ql * 4 + q]);
  union { unsigned i; float f; } plo, phi;
  plo.i = su << 16;
  phi.i = su & 0xFFFF0000u;
  const float sc = 1.0f + eps[0];
  v2f x;
  x.x = gelu_exact(fmaf(sc, plo.f, sel.x));
  x.y = gelu_exact(fmaf(sc, phi.f, sel.y));
  v2f* __restrict__ P2 = (v2f*)out;
  __builtin_nontemporal_store(x, &P2[(size_t)v * 64 + ql * 4 + q]);
}

extern "C" void kernel_launch(void* const* d_in, const int* in_sizes, int n_in,
                              void* d_out, int out_size, void* d_ws, size_t ws_size,
                              hipStream_t stream) {
  const float* X = (const float*)d_in[0];
  const float* W = (const float*)d_in[1];
  const float* eps = (const float*)d_in[2];
  const int* vertex = (const int*)d_in[3];
  const int* edges = (const int*)d_in[4];
  const int nnz = in_sizes[3];

  // workspace layout. CSR build runs BEFORE the GEMM, so staging S aliases Xb2.
  char* ws = (char*)d_ws;
  size_t off = 0;
  auto alloc = [&](size_t bytes) -> void* {
    void* p = ws + off;
    off = (off + bytes + 255) & ~(size_t)255;
    return p;
  };
  const size_t stagingB = ((size_t)NBE * CAP_E + (size_t)NBV * CAP_V) * 4;  // ~14.2 MB
  const size_t xbB = (size_t)NN * DD * 2;                                   // 25.6 MB
  void* A = alloc(xbB > stagingB ? xbB : stagingB);
  int* S = (int*)A;                          // staging slabs (dead after k_pass2)
  unsigned short* Xb2 = (unsigned short*)A;  // row-major bf16 Xp (born in k_gemm)
  unsigned* Xe2 = (unsigned*)alloc((size_t)NE * DD * 2);    // 12.8 MB bf16 Xe
  int* LE = (int*)alloc((size_t)nnz * sizeof(int));         // 6.4 MB (vertex ids)
  unsigned short* LV =
      (unsigned short*)alloc((size_t)nnz * sizeof(unsigned short));  // 3.2 MB (edge ids)
  int* O = (int*)alloc((size_t)(NSEG + 2) * sizeof(int));   // disjoint E/V regions
  int* gcur = (int*)alloc((size_t)NB * sizeof(int));
  unsigned short* Wt = (unsigned short*)alloc((size_t)DD * DD * 2);  // 32 KB bf16 W^T
  if (off > ws_size) return;

  k_init<<<67, 256, 0, stream>>>(gcur, W, Wt);
  k_pass1<<<(nnz + 4095) / 4096, 256, 0, stream>>>(vertex, edges, gcur, S, nnz);
  k_pass2<<<NB, 256, 0, stream>>>(gcur, S, LE, LV, O, nnz);
  k_gemm<<<(NN + 63) / 64, 256, 0, stream>>>(X, Wt, Xb2);
  k_edge_agg<<<NE / 4, 256, 0, stream>>>((const unsigned*)Xb2, O, LE, Xe2);
  k_vert_agg<<<NN / 4, 256, 0, stream>>>(Xe2, O, LV, eps, (const unsigned*)Xb2,
                                         (float*)d_out);
}